// Round 1
// baseline (73.965 us; speedup 1.0000x reference)
//
#include <hip/hip_runtime.h>

// Problem constants (from reference): B=4096, L=256, LOCAL_DIM=2, M=64
#define BQ 4096
#define LQ 256
#define MQ 64
// eps_t row stride: LOCAL_DIM * M = 128 floats per l
#define ROWQ 128

// Kernel 1: transpose epsilon[s][m][l] (2,64,256) -> eps_t[l][s][m] (256,2,64)
// 32768 elements total; coalesced writes, reads are strided but tiny (128 KB).
__global__ void qgps_transpose_eps(const float* __restrict__ eps,
                                   float* __restrict__ eps_t) {
    int tid = blockIdx.x * blockDim.x + threadIdx.x;  // 0..32767
    int m = tid & (MQ - 1);
    int s = (tid >> 6) & 1;
    int l = tid >> 7;
    eps_t[tid] = eps[s * (MQ * LQ) + m * LQ + l];
}

// Kernel 2: one wave (64 lanes) per sample row b. lane = m.
// out[b] = sum_m prod_l eps_t[l][samples[b,l]][m]
__global__ __launch_bounds__(256) void qgps_kernel(const int* __restrict__ samples,
                                                   const float* __restrict__ eps_t,
                                                   float* __restrict__ out) {
    const int wave = threadIdx.x >> 6;                 // 0..3
    const int lane = threadIdx.x & 63;                 // m index
    const int b = blockIdx.x * 4 + wave;

    const int4* srow4 = (const int4*)(samples + b * LQ);  // wave-uniform reads

    // 4 independent product chains to break the serial multiply dependency.
    float p0 = 1.0f, p1 = 1.0f, p2 = 1.0f, p3 = 1.0f;

#pragma unroll 8
    for (int l4 = 0; l4 < LQ / 4; ++l4) {
        const int4 s4 = srow4[l4];  // all 64 lanes same address -> broadcast
        const int l = l4 * 4;
        p0 *= eps_t[(l + 0) * ROWQ + s4.x * MQ + lane];
        p1 *= eps_t[(l + 1) * ROWQ + s4.y * MQ + lane];
        p2 *= eps_t[(l + 2) * ROWQ + s4.z * MQ + lane];
        p3 *= eps_t[(l + 3) * ROWQ + s4.w * MQ + lane];
    }
    float p = (p0 * p1) * (p2 * p3);

    // Butterfly reduction over the 64-lane wave (sum over m).
#pragma unroll
    for (int off = 32; off > 0; off >>= 1)
        p += __shfl_xor(p, off, 64);

    if (lane == 0) out[b] = p;
}

extern "C" void kernel_launch(void* const* d_in, const int* in_sizes, int n_in,
                              void* d_out, int out_size, void* d_ws, size_t ws_size,
                              hipStream_t stream) {
    const int* samples = (const int*)d_in[0];        // (B, L) int32
    const float* eps = (const float*)d_in[1];        // (LOCAL_DIM, M, L) fp32
    float* out = (float*)d_out;                      // (B,) fp32
    float* eps_t = (float*)d_ws;                     // 128 KB scratch

    // Transpose epsilon into eps_t[l][s][m]
    qgps_transpose_eps<<<(LQ * 2 * MQ) / 256, 256, 0, stream>>>(eps, eps_t);

    // Main kernel: 4 b's per 256-thread block
    qgps_kernel<<<BQ / 4, 256, 0, stream>>>(samples, eps_t, out);
}